// Round 1
// baseline (230.275 us; speedup 1.0000x reference)
//
#include <hip/hip_runtime.h>
#include <math.h>

#define BB 1024      // batch
#define DD 512       // feature dim
#define CC 50000     // classes
#define KMAX 1024    // max seen classes (<= B)
#define SCALE_F 16.0f
#define EPS_F 0.1f

// ---------------- K0: init counters ----------------
__global__ void k_init(int* counts, int* kctr, float* lossAcc) {
    int i = blockIdx.x * blockDim.x + threadIdx.x;
    if (i < CC) counts[i] = 0;
    if (i == 0) { *kctr = 0; *lossAcc = 0.0f; }
}

// ---------------- K1: histogram of targets ----------------
__global__ void k_count(const int* __restrict__ targets, int* counts) {
    int i = blockIdx.x * blockDim.x + threadIdx.x;
    if (i < BB) atomicAdd(&counts[targets[i]], 1);
}

// ---------------- K2: compact valid classes ----------------
__global__ void k_compact(const int* __restrict__ counts,
                          const int* __restrict__ lmem,
                          int* rank, int* sc, int* kctr) {
    int c = blockIdx.x * blockDim.x + threadIdx.x;
    if (c >= CC) return;
    bool valid = (counts[c] > 0) || (lmem[c] != -1);
    int r = -1;
    if (valid) {
        int slot = atomicAdd(kctr, 1);
        if (slot < KMAX) { sc[slot] = c; r = slot; }
    }
    rank[c] = r;
}

// ---------------- K3: per-class mean (sums) + L2 normalize ----------------
__global__ __launch_bounds__(256) void k_mnorm(const float* __restrict__ inputs,
                                               const float* __restrict__ fmem,
                                               const int* __restrict__ targets,
                                               const int* __restrict__ counts,
                                               const int* __restrict__ sc,
                                               const int* __restrict__ kctr,
                                               float* mnorm) {
    int k = blockIdx.x;
    int tid = threadIdx.x;
    int Kv = *kctr;
    if (k >= Kv) {   // zero pad rows so GEMM reads are defined
        for (int d = tid; d < DD; d += 256) mnorm[k * DD + d] = 0.0f;
        return;
    }
    int c = sc[k];
    __shared__ int tl[BB];
    for (int i = tid; i < BB; i += 256) tl[i] = targets[i];
    __syncthreads();
    int d0 = tid * 2;
    float a0 = 0.0f, a1 = 0.0f;
    if (counts[c] > 0) {
        for (int i = 0; i < BB; ++i) {
            if (tl[i] == c) {
                a0 += inputs[i * DD + d0];
                a1 += inputs[i * DD + d0 + 1];
            }
        }
        // note: /count cancels under normalization
    } else {
        a0 = fmem[(size_t)c * DD + d0];
        a1 = fmem[(size_t)c * DD + d0 + 1];
    }
    __shared__ float red[256];
    red[tid] = a0 * a0 + a1 * a1;
    __syncthreads();
    for (int s = 128; s > 0; s >>= 1) {
        if (tid < s) red[tid] += red[tid + s];
        __syncthreads();
    }
    float nrm = sqrtf(red[0]);
    float scale = 1.0f / fmaxf(nrm, 1e-12f);
    mnorm[k * DD + d0]     = a0 * scale;
    mnorm[k * DD + d0 + 1] = a1 * scale;
}

// ---------------- K4: normalize input rows ----------------
__global__ __launch_bounds__(256) void k_inorm(const float* __restrict__ inputs,
                                               float* inorm) {
    int b = blockIdx.x;
    int tid = threadIdx.x;
    int d0 = tid * 2;
    float a0 = inputs[b * DD + d0];
    float a1 = inputs[b * DD + d0 + 1];
    __shared__ float red[256];
    red[tid] = a0 * a0 + a1 * a1;
    __syncthreads();
    for (int s = 128; s > 0; s >>= 1) {
        if (tid < s) red[tid] += red[tid + s];
        __syncthreads();
    }
    float nrm = sqrtf(red[0]);
    float scale = 1.0f / fmaxf(nrm, 1e-12f);
    inorm[b * DD + d0]     = a0 * scale;
    inorm[b * DD + d0 + 1] = a1 * scale;
}

// ---------------- K5: gather positive_mask at seen columns ----------------
// one block per batch row; predicated load -> only lines containing a seen
// column are fetched from HBM (~28% of the 205MB).
__global__ __launch_bounds__(256) void k_gather(const float* __restrict__ pm,
                                                const int* __restrict__ rank,
                                                float* pmc) {
    int b = blockIdx.x;
    const float* row = pm + (size_t)b * CC;
    float* outp = pmc + (size_t)b * KMAX;
    for (int c = threadIdx.x; c < CC; c += 256) {
        int r = rank[c];
        if (r >= 0) outp[r] = row[c];
    }
}

// ---------------- K6: f32 GEMM  simc = 16 * inorm @ mnorm^T ----------------
#define TM 64
#define TN 64
#define TK 32
__global__ __launch_bounds__(256) void k_gemm(const float* __restrict__ inorm,
                                              const float* __restrict__ mnorm,
                                              float* simc) {
    __shared__ float As[TM][TK + 1];
    __shared__ float Bs[TN][TK + 1];
    int tid = threadIdx.x;
    int tx = tid & 15, ty = tid >> 4;
    int b0 = blockIdx.y * TM;
    int k0 = blockIdx.x * TN;
    float acc[4][4] = {};
    for (int dk = 0; dk < DD; dk += TK) {
        int row = tid >> 2;           // 0..63
        int col = (tid & 3) * 8;      // 0,8,16,24
        const float* srcA = inorm + (b0 + row) * DD + dk + col;
        const float* srcB = mnorm + (k0 + row) * DD + dk + col;
        #pragma unroll
        for (int j = 0; j < 8; ++j) As[row][col + j] = srcA[j];
        #pragma unroll
        for (int j = 0; j < 8; ++j) Bs[row][col + j] = srcB[j];
        __syncthreads();
        #pragma unroll
        for (int kk = 0; kk < TK; ++kk) {
            float ra[4], rb[4];
            #pragma unroll
            for (int i = 0; i < 4; ++i) ra[i] = As[ty * 4 + i][kk];
            #pragma unroll
            for (int j = 0; j < 4; ++j) rb[j] = Bs[tx * 4 + j][kk];
            #pragma unroll
            for (int i = 0; i < 4; ++i)
                #pragma unroll
                for (int j = 0; j < 4; ++j)
                    acc[i][j] += ra[i] * rb[j];
        }
        __syncthreads();
    }
    #pragma unroll
    for (int i = 0; i < 4; ++i) {
        int bb = b0 + ty * 4 + i;
        #pragma unroll
        for (int j = 0; j < 4; ++j) {
            int kk = k0 + tx * 4 + j;
            simc[(size_t)bb * KMAX + kk] = acc[i][j] * SCALE_F;
        }
    }
}

// ---------------- K7: per-row loss ----------------
__global__ __launch_bounds__(256) void k_loss(const float* __restrict__ simc,
                                              const float* __restrict__ pmc,
                                              const int* __restrict__ targets,
                                              const int* __restrict__ rank,
                                              const int* __restrict__ kctr,
                                              float* lossAcc) {
    int b = blockIdx.x;
    int tid = threadIdx.x;
    int Kv = *kctr;
    if (Kv > KMAX) Kv = KMAX;
    int rt = rank[targets[b]];
    const float* srow = simc + (size_t)b * KMAX;
    const float* prow = pmc + (size_t)b * KMAX;

    float sneg = 0.0f, psum = 0.0f;
    for (int k = tid; k < Kv; k += 256) {
        float pm = prow[k];
        float e = expf(srow[k]);
        sneg += (1.0f - pm) * e;
        psum += pm;
    }
    __shared__ float r1[256], r2[256];
    r1[tid] = sneg; r2[tid] = psum;
    __syncthreads();
    for (int s = 128; s > 0; s >>= 1) {
        if (tid < s) { r1[tid] += r1[tid + s]; r2[tid] += r2[tid + s]; }
        __syncthreads();
    }
    sneg = r1[0]; psum = r2[0];
    __syncthreads();   // protect r1/r2 reuse below

    float inv = EPS_F / psum;
    float acc = 0.0f;
    for (int k = tid; k < Kv; k += 256) {
        float pm = prow[k];
        float w = inv * pm + ((k == rt) ? (1.0f - EPS_F) : 0.0f);
        if (w != 0.0f) {
            float s = srow[k];
            acc += w * (s - logf(sneg + expf(s)));
        }
    }
    r1[tid] = acc;
    __syncthreads();
    for (int s = 128; s > 0; s >>= 1) {
        if (tid < s) r1[tid] += r1[tid + s];
        __syncthreads();
    }
    if (tid == 0) atomicAdd(lossAcc, -r1[0] * (1.0f / BB));
}

// ---------------- K8: write scalar out ----------------
__global__ void k_write(const float* lossAcc, float* outp) { outp[0] = *lossAcc; }

extern "C" void kernel_launch(void* const* d_in, const int* in_sizes, int n_in,
                              void* d_out, int out_size, void* d_ws, size_t ws_size,
                              hipStream_t stream) {
    const float* inputs  = (const float*)d_in[0];
    const float* pmask   = (const float*)d_in[1];
    const float* fmem    = (const float*)d_in[2];
    const int*   lmem    = (const int*)d_in[3];
    const int*   targets = (const int*)d_in[4];
    float* outp = (float*)d_out;

    char* ws = (char*)d_ws;
    size_t off = 0;
    auto alloc = [&](size_t bytes) -> void* {
        void* p = ws + off;
        off = (off + bytes + 255) & ~(size_t)255;
        return p;
    };
    int*   counts  = (int*)alloc(CC * sizeof(int));
    int*   rank    = (int*)alloc(CC * sizeof(int));
    int*   sc      = (int*)alloc(KMAX * sizeof(int));
    int*   kctr    = (int*)alloc(sizeof(int));
    float* lossAcc = (float*)alloc(sizeof(float));
    float* inorm   = (float*)alloc((size_t)BB * DD * sizeof(float));
    float* mnorm   = (float*)alloc((size_t)KMAX * DD * sizeof(float));
    float* pmc     = (float*)alloc((size_t)BB * KMAX * sizeof(float));
    float* simc    = (float*)alloc((size_t)BB * KMAX * sizeof(float));

    k_init<<<(CC + 255) / 256, 256, 0, stream>>>(counts, kctr, lossAcc);
    k_count<<<(BB + 255) / 256, 256, 0, stream>>>(targets, counts);
    k_compact<<<(CC + 255) / 256, 256, 0, stream>>>(counts, lmem, rank, sc, kctr);
    k_mnorm<<<KMAX, 256, 0, stream>>>(inputs, fmem, targets, counts, sc, kctr, mnorm);
    k_inorm<<<BB, 256, 0, stream>>>(inputs, inorm);
    k_gather<<<BB, 256, 0, stream>>>(pmask, rank, pmc);
    dim3 g6(KMAX / TN, BB / TM);
    k_gemm<<<g6, 256, 0, stream>>>(inorm, mnorm, simc);
    k_loss<<<BB, 256, 0, stream>>>(simc, pmc, targets, rank, kctr, lossAcc);
    k_write<<<1, 1, 0, stream>>>(lossAcc, outp);
}

// Round 2
// 85.498 us; speedup vs baseline: 2.6933x; 2.6933x over previous
//
#include <hip/hip_runtime.h>
#include <math.h>

#define BB 1024      // batch
#define DD 512       // feature dim
#define CC 50000     // classes
#define KMAX 1024    // max compacted classes (<= B when label_memory is all -1)
#define SCALE_F 16.0f
#define EPS_F 0.1f

// ---------------- K0: init counters + zero msum ----------------
__global__ void k_init(int* counts, int* kctr, float* lossAcc, float* msum) {
    int i = blockIdx.x * blockDim.x + threadIdx.x;
    if (i < CC) counts[i] = 0;
    if (i < KMAX * DD) msum[i] = 0.0f;
    if (i == 0) { *kctr = 0; *lossAcc = 0.0f; }
}

// ---------------- K1: histogram of targets ----------------
__global__ void k_count(const int* __restrict__ targets, int* counts) {
    int i = blockIdx.x * blockDim.x + threadIdx.x;
    if (i < BB) atomicAdd(&counts[targets[i]], 1);
}

// ---------------- K2: compact valid classes ----------------
__global__ void k_compact(const int* __restrict__ counts,
                          const int* __restrict__ lmem,
                          int* rank, int* sc, int* kctr) {
    int c = blockIdx.x * blockDim.x + threadIdx.x;
    if (c >= CC) return;
    bool valid = (counts[c] > 0) || (lmem[c] != -1);
    int r = -1;
    if (valid) {
        int slot = atomicAdd(kctr, 1);
        if (slot < KMAX) { sc[slot] = c; r = slot; }
    }
    rank[c] = r;
}

// ---------------- K3a: scatter-add inputs into per-class sums ----------------
__global__ void k_scatter(const float* __restrict__ inputs,
                          const int* __restrict__ targets,
                          const int* __restrict__ rank,
                          const int* __restrict__ counts,
                          float* msum) {
    int idx = blockIdx.x * blockDim.x + threadIdx.x;   // over BB*DD
    int b = idx >> 9;            // DD = 512
    int d = idx & (DD - 1);
    int c = targets[b];
    int k = rank[c];
    if (k < 0) return;
    float v = inputs[idx];
    if (counts[c] == 1) msum[k * DD + d] = v;          // unique row: plain store
    else atomicAdd(&msum[k * DD + d], v);
}

// ---------------- K3b: per-class L2 normalize (sums; /count cancels) ----------
__global__ __launch_bounds__(256) void k_mnorm(const float* __restrict__ msum,
                                               const float* __restrict__ fmem,
                                               const int* __restrict__ counts,
                                               const int* __restrict__ sc,
                                               const int* __restrict__ kctr,
                                               float* mnorm) {
    int k = blockIdx.x;
    int tid = threadIdx.x;
    int Kv = *kctr; if (Kv > KMAX) Kv = KMAX;
    int d0 = tid * 2;
    float a0 = 0.0f, a1 = 0.0f;
    if (k < Kv) {
        int c = sc[k];
        if (counts[c] > 0) {
            a0 = msum[k * DD + d0];
            a1 = msum[k * DD + d0 + 1];
        } else {
            a0 = fmem[(size_t)c * DD + d0];
            a1 = fmem[(size_t)c * DD + d0 + 1];
        }
    }
    __shared__ float red[256];
    red[tid] = a0 * a0 + a1 * a1;
    __syncthreads();
    for (int s = 128; s > 0; s >>= 1) {
        if (tid < s) red[tid] += red[tid + s];
        __syncthreads();
    }
    float scale = 1.0f / fmaxf(sqrtf(red[0]), 1e-12f);  // k>=Kv: 0*1e12 = 0
    mnorm[k * DD + d0]     = a0 * scale;
    mnorm[k * DD + d0 + 1] = a1 * scale;
}

// ---------------- K4: normalize input rows ----------------
__global__ __launch_bounds__(256) void k_inorm(const float* __restrict__ inputs,
                                               float* inorm) {
    int b = blockIdx.x;
    int tid = threadIdx.x;
    int d0 = tid * 2;
    float a0 = inputs[b * DD + d0];
    float a1 = inputs[b * DD + d0 + 1];
    __shared__ float red[256];
    red[tid] = a0 * a0 + a1 * a1;
    __syncthreads();
    for (int s = 128; s > 0; s >>= 1) {
        if (tid < s) red[tid] += red[tid + s];
        __syncthreads();
    }
    float scale = 1.0f / fmaxf(sqrtf(red[0]), 1e-12f);
    inorm[b * DD + d0]     = a0 * scale;
    inorm[b * DD + d0 + 1] = a1 * scale;
}

// ---------------- K6: f32 GEMM  simc = 16 * inorm @ mnorm^T ----------------
// LDS tiles stored K-major so inner loop is 2x ds_read_b128 + 16 FMA.
#define TM 64
#define TN 64
#define TK 32
__global__ __launch_bounds__(256) void k_gemm(const float* __restrict__ inorm,
                                              const float* __restrict__ mnorm,
                                              float* __restrict__ simc) {
    __shared__ float As[TK][TM + 4];
    __shared__ float Bs[TK][TN + 4];
    int tid = threadIdx.x;
    int tx = tid & 15, ty = tid >> 4;
    int b0 = blockIdx.y * TM;
    int k0 = blockIdx.x * TN;
    float acc[4][4] = {};
    int row = tid >> 2;             // 0..63
    int col = (tid & 3) * 8;        // 0,8,16,24
    const float* srcA = inorm + (b0 + row) * DD + col;
    const float* srcB = mnorm + (k0 + row) * DD + col;
    for (int dk = 0; dk < DD; dk += TK) {
        #pragma unroll
        for (int j = 0; j < 8; ++j) As[col + j][row] = srcA[dk + j];
        #pragma unroll
        for (int j = 0; j < 8; ++j) Bs[col + j][row] = srcB[dk + j];
        __syncthreads();
        #pragma unroll
        for (int kk = 0; kk < TK; ++kk) {
            float ra[4], rb[4];
            *(float4*)ra = *(const float4*)&As[kk][ty * 4];
            *(float4*)rb = *(const float4*)&Bs[kk][tx * 4];
            #pragma unroll
            for (int i = 0; i < 4; ++i)
                #pragma unroll
                for (int j = 0; j < 4; ++j)
                    acc[i][j] += ra[i] * rb[j];
        }
        __syncthreads();
    }
    #pragma unroll
    for (int i = 0; i < 4; ++i) {
        int bb = b0 + ty * 4 + i;
        float4 st;
        st.x = acc[i][0] * SCALE_F; st.y = acc[i][1] * SCALE_F;
        st.z = acc[i][2] * SCALE_F; st.w = acc[i][3] * SCALE_F;
        *(float4*)&simc[(size_t)bb * KMAX + k0 + tx * 4] = st;
    }
}

// ---------------- K7: fused gather + per-row loss ----------------
__global__ __launch_bounds__(256) void k_loss(const float* __restrict__ simc,
                                              const float* __restrict__ pm,
                                              const int* __restrict__ sc,
                                              const int* __restrict__ targets,
                                              const int* __restrict__ rank,
                                              const int* __restrict__ kctr,
                                              float* lossAcc) {
    int b = blockIdx.x;
    int tid = threadIdx.x;
    int Kv = *kctr; if (Kv > KMAX) Kv = KMAX;
    __shared__ float pm_s[KMAX];
    const float* __restrict__ row = pm + (size_t)b * CC;
    for (int k = tid; k < Kv; k += 256) pm_s[k] = row[sc[k]];   // scattered gather
    int rt = rank[targets[b]];
    const float* srow = simc + (size_t)b * KMAX;
    __syncthreads();

    float sneg = 0.0f, psum = 0.0f;
    for (int k = tid; k < Kv; k += 256) {
        float pmv = pm_s[k];
        float e = expf(srow[k]);
        sneg += (1.0f - pmv) * e;
        psum += pmv;
    }
    __shared__ float r1[256], r2[256];
    r1[tid] = sneg; r2[tid] = psum;
    __syncthreads();
    for (int s = 128; s > 0; s >>= 1) {
        if (tid < s) { r1[tid] += r1[tid + s]; r2[tid] += r2[tid + s]; }
        __syncthreads();
    }
    sneg = r1[0]; psum = r2[0];
    __syncthreads();

    float inv = EPS_F / psum;
    float acc = 0.0f;
    for (int k = tid; k < Kv; k += 256) {
        float w = inv * pm_s[k] + ((k == rt) ? (1.0f - EPS_F) : 0.0f);
        if (w != 0.0f) {
            float s = srow[k];
            acc += w * (s - logf(sneg + expf(s)));
        }
    }
    r1[tid] = acc;
    __syncthreads();
    for (int s = 128; s > 0; s >>= 1) {
        if (tid < s) r1[tid] += r1[tid + s];
        __syncthreads();
    }
    if (tid == 0) atomicAdd(lossAcc, -r1[0] * (1.0f / BB));
}

// ---------------- K8: write scalar out ----------------
__global__ void k_write(const float* lossAcc, float* outp) { outp[0] = *lossAcc; }

extern "C" void kernel_launch(void* const* d_in, const int* in_sizes, int n_in,
                              void* d_out, int out_size, void* d_ws, size_t ws_size,
                              hipStream_t stream) {
    const float* inputs  = (const float*)d_in[0];
    const float* pmask   = (const float*)d_in[1];
    const float* fmem    = (const float*)d_in[2];
    const int*   lmem    = (const int*)d_in[3];
    const int*   targets = (const int*)d_in[4];
    float* outp = (float*)d_out;

    char* ws = (char*)d_ws;
    size_t off = 0;
    auto alloc = [&](size_t bytes) -> void* {
        void* p = ws + off;
        off = (off + bytes + 255) & ~(size_t)255;
        return p;
    };
    int*   counts  = (int*)alloc(CC * sizeof(int));
    int*   rank    = (int*)alloc(CC * sizeof(int));
    int*   sc      = (int*)alloc(KMAX * sizeof(int));
    int*   kctr    = (int*)alloc(sizeof(int));
    float* lossAcc = (float*)alloc(sizeof(float));
    float* msum    = (float*)alloc((size_t)KMAX * DD * sizeof(float));
    float* inorm   = (float*)alloc((size_t)BB * DD * sizeof(float));
    float* mnorm   = (float*)alloc((size_t)KMAX * DD * sizeof(float));
    float* simc    = (float*)alloc((size_t)BB * KMAX * sizeof(float));

    k_init<<<(KMAX * DD + 255) / 256, 256, 0, stream>>>(counts, kctr, lossAcc, msum);
    k_count<<<(BB + 255) / 256, 256, 0, stream>>>(targets, counts);
    k_compact<<<(CC + 255) / 256, 256, 0, stream>>>(counts, lmem, rank, sc, kctr);
    k_scatter<<<(BB * DD + 255) / 256, 256, 0, stream>>>(inputs, targets, rank, counts, msum);
    k_mnorm<<<KMAX, 256, 0, stream>>>(msum, fmem, counts, sc, kctr, mnorm);
    k_inorm<<<BB, 256, 0, stream>>>(inputs, inorm);
    dim3 g6(KMAX / TN, BB / TM);
    k_gemm<<<g6, 256, 0, stream>>>(inorm, mnorm, simc);
    k_loss<<<BB, 256, 0, stream>>>(simc, pmask, sc, targets, rank, kctr, lossAcc);
    k_write<<<1, 1, 0, stream>>>(lossAcc, outp);
}

// Round 3
// 80.387 us; speedup vs baseline: 2.8646x; 1.0636x over previous
//
#include <hip/hip_runtime.h>
#include <math.h>

#define BB 1024      // batch
#define DD 512       // feature dim
#define CC 50000     // classes
#define KMAX 1024    // max compacted classes
#define HSZ 2048     // LDS hash size
#define SCALE_F 16.0f
#define EPS_F 0.1f

typedef __bf16 bf16_t;
typedef bf16_t bf16x8 __attribute__((ext_vector_type(8)));
typedef float f32x4 __attribute__((ext_vector_type(4)));

// ---------------- K1: prep — dedup targets via LDS hash, ranks, lmem scan ----
__global__ __launch_bounds__(1024) void k_prep(const int* __restrict__ targets,
                                               const int* __restrict__ lmem,
                                               int* sc, int* rowrank,
                                               int* kctr, float* lossAcc) {
    __shared__ int hkey[HSZ];
    __shared__ int hval[HSZ];
    __shared__ int kc;
    int tid = threadIdx.x;
    hkey[tid] = -1; hkey[tid + 1024] = -1;
    if (tid == 0) kc = 0;
    __syncthreads();

    int c = targets[tid];
    unsigned h = ((unsigned)c * 2654435761u) >> 21;   // 0..2047
    int myslot;
    while (true) {
        int old = atomicCAS(&hkey[h], -1, c);
        if (old == -1) {                 // I own this class
            int r = atomicAdd(&kc, 1);
            hval[h] = r;
            sc[r] = c;
            myslot = (int)h;
            break;
        } else if (old == c) { myslot = (int)h; break; }
        h = (h + 1) & (HSZ - 1);
    }

    // classes valid via label_memory (rare; lmem is all -1 in this workload)
    for (int cc2 = tid; cc2 < CC; cc2 += 1024) {
        if (lmem[cc2] != -1) {
            unsigned hh = ((unsigned)cc2 * 2654435761u) >> 21;
            while (true) {
                int old = atomicCAS(&hkey[hh], -1, cc2);
                if (old == -1) {
                    int r = atomicAdd(&kc, 1);
                    if (r < KMAX) sc[r] = cc2;
                    break;
                } else if (old == cc2) break;
                hh = (hh + 1) & (HSZ - 1);
            }
        }
    }
    __syncthreads();
    rowrank[tid] = hval[myslot];
    if (tid == 0) { *kctr = kc < KMAX ? kc : KMAX; *lossAcc = 0.0f; }
}

// ---------------- K2: per-class mean + L2 normalize + bf16 hi/lo split -------
__global__ __launch_bounds__(256) void k_mnorm(const float* __restrict__ inputs,
                                               const float* __restrict__ fmem,
                                               const int* __restrict__ targets,
                                               const int* __restrict__ sc,
                                               const int* __restrict__ kctr,
                                               bf16_t* __restrict__ BH,
                                               bf16_t* __restrict__ BL) {
    int k = blockIdx.x;
    int tid = threadIdx.x;
    int Kv = *kctr;
    int d0 = tid * 2;
    if (k >= Kv) {                        // zero-pad rows so GEMM reads 0
        BH[k * DD + d0] = (bf16_t)0.0f; BH[k * DD + d0 + 1] = (bf16_t)0.0f;
        BL[k * DD + d0] = (bf16_t)0.0f; BL[k * DD + d0 + 1] = (bf16_t)0.0f;
        return;
    }
    int c = sc[k];
    __shared__ int members[BB];
    __shared__ int mcount;
    if (tid == 0) mcount = 0;
    __syncthreads();
    int4 t4 = *(const int4*)(targets + tid * 4);
    if (t4.x == c) { int s = atomicAdd(&mcount, 1); members[s] = tid * 4 + 0; }
    if (t4.y == c) { int s = atomicAdd(&mcount, 1); members[s] = tid * 4 + 1; }
    if (t4.z == c) { int s = atomicAdd(&mcount, 1); members[s] = tid * 4 + 2; }
    if (t4.w == c) { int s = atomicAdd(&mcount, 1); members[s] = tid * 4 + 3; }
    __syncthreads();
    int mc = mcount;
    float a0 = 0.0f, a1 = 0.0f;
    if (mc == 0) {                        // unseen but lmem-valid: memory row
        a0 = fmem[(size_t)c * DD + d0];
        a1 = fmem[(size_t)c * DD + d0 + 1];
    } else {                              // sum member rows (/count cancels)
        for (int i = 0; i < mc; ++i) {
            int b = members[i];
            a0 += inputs[b * DD + d0];
            a1 += inputs[b * DD + d0 + 1];
        }
    }
    __shared__ float red[256];
    red[tid] = a0 * a0 + a1 * a1;
    __syncthreads();
    for (int s = 128; s > 0; s >>= 1) {
        if (tid < s) red[tid] += red[tid + s];
        __syncthreads();
    }
    float scale = 1.0f / fmaxf(sqrtf(red[0]), 1e-12f);
    a0 *= scale; a1 *= scale;
    bf16_t h0 = (bf16_t)a0, h1 = (bf16_t)a1;
    BH[k * DD + d0]     = h0; BH[k * DD + d0 + 1] = h1;
    BL[k * DD + d0]     = (bf16_t)(a0 - (float)h0);
    BL[k * DD + d0 + 1] = (bf16_t)(a1 - (float)h1);
}

// ---------------- K3: normalize input rows + bf16 hi/lo split ----------------
__global__ __launch_bounds__(256) void k_inorm(const float* __restrict__ inputs,
                                               bf16_t* __restrict__ AH,
                                               bf16_t* __restrict__ AL) {
    int b = blockIdx.x;
    int tid = threadIdx.x;
    int d0 = tid * 2;
    float a0 = inputs[b * DD + d0];
    float a1 = inputs[b * DD + d0 + 1];
    __shared__ float red[256];
    red[tid] = a0 * a0 + a1 * a1;
    __syncthreads();
    for (int s = 128; s > 0; s >>= 1) {
        if (tid < s) red[tid] += red[tid + s];
        __syncthreads();
    }
    float scale = 1.0f / fmaxf(sqrtf(red[0]), 1e-12f);
    a0 *= scale; a1 *= scale;
    bf16_t h0 = (bf16_t)a0, h1 = (bf16_t)a1;
    AH[b * DD + d0]     = h0; AH[b * DD + d0 + 1] = h1;
    AL[b * DD + d0]     = (bf16_t)(a0 - (float)h0);
    AL[b * DD + d0 + 1] = (bf16_t)(a1 - (float)h1);
}

// ---------------- K4: MFMA GEMM  simc = 16 * inorm @ mnorm^T -----------------
// bf16 3-term split: Ah*Bh + Ah*Bl + Al*Bh, fp32 accumulate.
// 64x64 tile per block, 4 waves, each wave a 32x32 quadrant; operands are
// L2-resident (4 MB) -> direct global fragment loads, no LDS.
__global__ __launch_bounds__(256) void k_gemm(const bf16_t* __restrict__ AH,
                                              const bf16_t* __restrict__ AL,
                                              const bf16_t* __restrict__ BH,
                                              const bf16_t* __restrict__ BL,
                                              float* __restrict__ simc) {
    int wave = threadIdx.x >> 6;
    int lane = threadIdx.x & 63;
    int b0 = blockIdx.y * 64 + (wave >> 1) * 32;
    int k0 = blockIdx.x * 64 + (wave & 1) * 32;
    int frow = lane & 15;              // A-row / B-col within fragment
    int koff = (lane >> 4) * 8;        // k offset within fragment
    f32x4 acc[2][2] = {};
    for (int dk = 0; dk < DD; dk += 32) {
        bf16x8 ah[2], al[2], bh[2], bl[2];
        #pragma unroll
        for (int i = 0; i < 2; ++i) {
            size_t ao = (size_t)(b0 + i * 16 + frow) * DD + dk + koff;
            size_t bo = (size_t)(k0 + i * 16 + frow) * DD + dk + koff;
            ah[i] = *(const bf16x8*)(AH + ao);
            al[i] = *(const bf16x8*)(AL + ao);
            bh[i] = *(const bf16x8*)(BH + bo);
            bl[i] = *(const bf16x8*)(BL + bo);
        }
        #pragma unroll
        for (int mi = 0; mi < 2; ++mi)
            #pragma unroll
            for (int ni = 0; ni < 2; ++ni) {
                acc[mi][ni] = __builtin_amdgcn_mfma_f32_16x16x32_bf16(ah[mi], bh[ni], acc[mi][ni], 0, 0, 0);
                acc[mi][ni] = __builtin_amdgcn_mfma_f32_16x16x32_bf16(ah[mi], bl[ni], acc[mi][ni], 0, 0, 0);
                acc[mi][ni] = __builtin_amdgcn_mfma_f32_16x16x32_bf16(al[mi], bh[ni], acc[mi][ni], 0, 0, 0);
            }
    }
    // C/D layout: col = lane&15, row = (lane>>4)*4 + reg
    int r4 = (lane >> 4) * 4;
    int cn = lane & 15;
    #pragma unroll
    for (int mi = 0; mi < 2; ++mi)
        #pragma unroll
        for (int ni = 0; ni < 2; ++ni)
            #pragma unroll
            for (int r = 0; r < 4; ++r)
                simc[(size_t)(b0 + mi * 16 + r4 + r) * KMAX + (k0 + ni * 16 + cn)]
                    = acc[mi][ni][r] * SCALE_F;
}

// ---------------- K5: fused gather + per-row loss ----------------------------
__global__ __launch_bounds__(256) void k_loss(const float* __restrict__ simc,
                                              const float* __restrict__ pm,
                                              const int* __restrict__ sc,
                                              const int* __restrict__ rowrank,
                                              const int* __restrict__ kctr,
                                              float* lossAcc) {
    int b = blockIdx.x;
    int tid = threadIdx.x;
    int Kv = *kctr;
    __shared__ float pm_s[KMAX];
    __shared__ float s_s[KMAX];
    const float* __restrict__ row = pm + (size_t)b * CC;
    const float* __restrict__ srow = simc + (size_t)b * KMAX;
    for (int k = tid; k < Kv; k += 256) {
        pm_s[k] = row[sc[k]];          // scattered gather of seen columns
        s_s[k] = srow[k];
    }
    int rt = rowrank[b];
    __syncthreads();

    float sneg = 0.0f, psum = 0.0f;
    for (int k = tid; k < Kv; k += 256) {
        float pmv = pm_s[k];
        sneg += (1.0f - pmv) * expf(s_s[k]);
        psum += pmv;
    }
    __shared__ float r1[256], r2[256];
    r1[tid] = sneg; r2[tid] = psum;
    __syncthreads();
    for (int s = 128; s > 0; s >>= 1) {
        if (tid < s) { r1[tid] += r1[tid + s]; r2[tid] += r2[tid + s]; }
        __syncthreads();
    }
    sneg = r1[0]; psum = r2[0];
    __syncthreads();

    float inv = EPS_F / psum;
    float acc = 0.0f;
    for (int k = tid; k < Kv; k += 256) {
        float w = inv * pm_s[k] + ((k == rt) ? (1.0f - EPS_F) : 0.0f);
        if (w != 0.0f) {
            float s = s_s[k];
            acc += w * (s - logf(sneg + expf(s)));
        }
    }
    r1[tid] = acc;
    __syncthreads();
    for (int s = 128; s > 0; s >>= 1) {
        if (tid < s) r1[tid] += r1[tid + s];
        __syncthreads();
    }
    if (tid == 0) atomicAdd(lossAcc, -r1[0] * (1.0f / BB));
}

// ---------------- K6: write scalar out ---------------------------------------
__global__ void k_write(const float* lossAcc, float* outp) { outp[0] = *lossAcc; }

extern "C" void kernel_launch(void* const* d_in, const int* in_sizes, int n_in,
                              void* d_out, int out_size, void* d_ws, size_t ws_size,
                              hipStream_t stream) {
    const float* inputs  = (const float*)d_in[0];
    const float* pmask   = (const float*)d_in[1];
    const float* fmem    = (const float*)d_in[2];
    const int*   lmem    = (const int*)d_in[3];
    const int*   targets = (const int*)d_in[4];
    float* outp = (float*)d_out;

    char* ws = (char*)d_ws;
    size_t off = 0;
    auto alloc = [&](size_t bytes) -> void* {
        void* p = ws + off;
        off = (off + bytes + 255) & ~(size_t)255;
        return p;
    };
    int*    sc      = (int*)alloc(KMAX * sizeof(int));
    int*    rowrank = (int*)alloc(BB * sizeof(int));
    int*    kctr    = (int*)alloc(sizeof(int));
    float*  lossAcc = (float*)alloc(sizeof(float));
    bf16_t* AH      = (bf16_t*)alloc((size_t)BB * DD * sizeof(bf16_t));
    bf16_t* AL      = (bf16_t*)alloc((size_t)BB * DD * sizeof(bf16_t));
    bf16_t* BH      = (bf16_t*)alloc((size_t)KMAX * DD * sizeof(bf16_t));
    bf16_t* BL      = (bf16_t*)alloc((size_t)KMAX * DD * sizeof(bf16_t));
    float*  simc    = (float*)alloc((size_t)BB * KMAX * sizeof(float));

    k_prep<<<1, 1024, 0, stream>>>(targets, lmem, sc, rowrank, kctr, lossAcc);
    k_mnorm<<<KMAX, 256, 0, stream>>>(inputs, fmem, targets, sc, kctr, BH, BL);
    k_inorm<<<BB, 256, 0, stream>>>(inputs, AH, AL);
    dim3 g4(KMAX / 64, BB / 64);
    k_gemm<<<g4, 256, 0, stream>>>(AH, AL, BH, BL, simc);
    k_loss<<<BB, 256, 0, stream>>>(simc, pmask, sc, rowrank, kctr, lossAcc);
    k_write<<<1, 1, 0, stream>>>(lossAcc, outp);
}